// Round 14
// baseline (16223.465 us; speedup 1.0000x reference)
//
#include <hip/hip_runtime.h>
#include <hip/hip_bf16.h>
#include <float.h>

#define KDIM 512
#define MBLK 64
#define NBLK 256
#define KBLK 16
#define NTH  256
#define APAD 68    // 64+4
#define BPAD 260   // 256+4
#define TOPK 8

// f32 whose high 16 bits are the RNE bf16 of v.
__device__ __forceinline__ float bf16_rne_f32(float v) {
  return __bfloat162float(__float2bfloat16(v));
}

// ---- row L2 norms in EXACT numpy pairwise order (unchanged from R13) -----
__global__ void er_norms(const float* __restrict__ T, const float* __restrict__ S,
                         float* __restrict__ nt, float* __restrict__ ns,
                         int M, int N) {
  int gid = blockIdx.x * blockDim.x + threadIdx.x;
  int row = gid >> 2;
  int b   = gid & 3;
  if (row >= M + N) return;
  const float* base = (row < M) ? (T + (size_t)row * KDIM)
                                : (S + (size_t)(row - M) * KDIM);
  const float4* p4 = (const float4*)(base + b * 128);
  float r[8];
  {
    float4 f0 = p4[0], f1 = p4[1];
    r[0] = __fmul_rn(f0.x, f0.x); r[1] = __fmul_rn(f0.y, f0.y);
    r[2] = __fmul_rn(f0.z, f0.z); r[3] = __fmul_rn(f0.w, f0.w);
    r[4] = __fmul_rn(f1.x, f1.x); r[5] = __fmul_rn(f1.y, f1.y);
    r[6] = __fmul_rn(f1.z, f1.z); r[7] = __fmul_rn(f1.w, f1.w);
  }
  #pragma unroll
  for (int i = 2; i < 32; i += 2) {
    float4 f0 = p4[i], f1 = p4[i + 1];
    r[0] = __fadd_rn(r[0], __fmul_rn(f0.x, f0.x));
    r[1] = __fadd_rn(r[1], __fmul_rn(f0.y, f0.y));
    r[2] = __fadd_rn(r[2], __fmul_rn(f0.z, f0.z));
    r[3] = __fadd_rn(r[3], __fmul_rn(f0.w, f0.w));
    r[4] = __fadd_rn(r[4], __fmul_rn(f1.x, f1.x));
    r[5] = __fadd_rn(r[5], __fmul_rn(f1.y, f1.y));
    r[6] = __fadd_rn(r[6], __fmul_rn(f1.z, f1.z));
    r[7] = __fadd_rn(r[7], __fmul_rn(f1.w, f1.w));
  }
  float B = __fadd_rn(__fadd_rn(__fadd_rn(r[0], r[1]), __fadd_rn(r[2], r[3])),
                      __fadd_rn(__fadd_rn(r[4], r[5]), __fadd_rn(r[6], r[7])));
  float t = __fadd_rn(B, __shfl_xor(B, 1, 64));
  float s = __fadd_rn(t, __shfl_xor(t, 2, 64));
  if (b == 0) {
    float nr = __fsqrt_rn(s);
    if (row < M) nt[row] = nr; else ns[row - M] = nr;
  }
}

// ---- candidate pass: normalized-f32 GEMM + per-split top-8 ---------------
// N-split for occupancy: grid = mblocks*nsplit, 4 blocks/CU. Score bits are
// IDENTICAL to the R13 kernel (same __fdiv_rn staging, same sequential-k
// fmaf chain, same __fadd_rn bias add) — only the column partition changed.
__global__ __launch_bounds__(NTH, 4)
void er_cand(const float* __restrict__ A, const float* __restrict__ B,
             const float* __restrict__ imp,
             const float* __restrict__ nt, const float* __restrict__ ns,
             float* __restrict__ pval, int* __restrict__ pidx,
             int M, int N, int nsplit, int mblocks) {
  __shared__ float a_lds[KBLK][APAD];
  __shared__ float b_lds[KBLK][BPAD];
  __shared__ float tval[MBLK][TOPK];
  __shared__ int   tidx[MBLK][TOPK];
  __shared__ float tthr[MBLK];

  const int tid    = threadIdx.x;
  const int mb     = blockIdx.x % mblocks;
  const int split  = blockIdx.x / mblocks;
  const int m_base = mb * MBLK;
  const int n_cols = N / nsplit;
  const int n_start = split * n_cols;
  const int ntiles  = n_cols / NBLK;
  const int tm = tid >> 5;        // rows tm*8..tm*8+7 (wave-exclusive)
  const int tn = tid & 31;        // cols tn*8..tn*8+7
  const int lane = tid & 63;

  if (tid < MBLK) {
    tthr[tid] = -FLT_MAX;
    #pragma unroll
    for (int j = 0; j < TOPK; ++j) { tval[tid][j] = -FLT_MAX; tidx[tid][j] = 0; }
  }
  __syncthreads();

  const int srow = tid >> 2;      // staging row (A: 0..63, B: +256*ii)
  const int sks  = tid & 3;       // staging k-quad

  #pragma unroll 1
  for (int t = 0; t < ntiles; ++t) {
    const int n_base = n_start + t * NBLK;
    float acc[8][8];
    #pragma unroll
    for (int i = 0; i < 8; ++i)
      #pragma unroll
      for (int j = 0; j < 8; ++j) acc[i][j] = 0.f;

    float4 ar, br[4];
    ar = *(const float4*)&A[(size_t)(m_base + srow) * KDIM + sks * 4];
    #pragma unroll
    for (int ii = 0; ii < 4; ++ii) {
      int u = tid + NTH * ii, row = u >> 2, ks = u & 3;
      br[ii] = *(const float4*)&B[(size_t)(n_base + row) * KDIM + ks * 4];
    }

    #pragma unroll 1
    for (int kc = 0; kc < KDIM / KBLK; ++kc) {
      __syncthreads();
      {   // stage A normalized: x / max(||row||, eps)   (bit-same as R13)
        float dn = fmaxf(nt[m_base + srow], 1e-12f);
        a_lds[sks*4+0][srow] = __fdiv_rn(ar.x, dn);
        a_lds[sks*4+1][srow] = __fdiv_rn(ar.y, dn);
        a_lds[sks*4+2][srow] = __fdiv_rn(ar.z, dn);
        a_lds[sks*4+3][srow] = __fdiv_rn(ar.w, dn);
      }
      #pragma unroll
      for (int ii = 0; ii < 4; ++ii) {
        int u = tid + NTH * ii, row = u >> 2, ks = u & 3;
        float dn = fmaxf(ns[n_base + row], 1e-12f);
        b_lds[ks*4+0][row] = __fdiv_rn(br[ii].x, dn);
        b_lds[ks*4+1][row] = __fdiv_rn(br[ii].y, dn);
        b_lds[ks*4+2][row] = __fdiv_rn(br[ii].z, dn);
        b_lds[ks*4+3][row] = __fdiv_rn(br[ii].w, dn);
      }
      __syncthreads();
      if (kc + 1 < KDIM / KBLK) {
        int kb = (kc + 1) * KBLK;
        ar = *(const float4*)&A[(size_t)(m_base + srow) * KDIM + kb + sks * 4];
        #pragma unroll
        for (int ii = 0; ii < 4; ++ii) {
          int u = tid + NTH * ii, row = u >> 2, ks = u & 3;
          br[ii] = *(const float4*)&B[(size_t)(n_base + row) * KDIM + kb + ks * 4];
        }
      }
      // sequential-k FMA chain, k ascending — bit-identical to R13
      #pragma unroll 16
      for (int k = 0; k < KBLK; ++k) {
        const float4* ap = (const float4*)&a_lds[k][tm * 8];
        const float4* bp = (const float4*)&b_lds[k][tn * 8];
        float4 a0 = ap[0], a1 = ap[1], b0 = bp[0], b1 = bp[1];
        float av[8] = {a0.x,a0.y,a0.z,a0.w,a1.x,a1.y,a1.z,a1.w};
        float bw[8] = {b0.x,b0.y,b0.z,b0.w,b1.x,b1.y,b1.z,b1.w};
        #pragma unroll
        for (int i = 0; i < 8; ++i)
          #pragma unroll
          for (int j = 0; j < 8; ++j)
            acc[i][j] = fmaf(av[i], bw[j], acc[i][j]);
      }
    }

    // epilogue: score = dot + bias (separate RNE add), running top-8
    float bv[8];
    #pragma unroll
    for (int j = 0; j < 8; ++j) bv[j] = __fmul_rn(0.1f, imp[n_base + tn * 8 + j]);

    int need = 0;
    #pragma unroll
    for (int i = 0; i < 8; ++i) {
      float thr = tthr[tm * 8 + i];
      #pragma unroll
      for (int j = 0; j < 8; ++j) {
        float s = __fadd_rn(acc[i][j], bv[j]);
        need |= (s > thr) ? 1 : 0;
      }
    }
    unsigned long long mask = __ballot(need);
    while (mask) {                       // ascending lane == ascending n
      int cur = __ffsll(mask) - 1;
      mask &= mask - 1;
      if (lane == cur) {
        #pragma unroll
        for (int i = 0; i < 8; ++i) {
          int r = tm * 8 + i;
          #pragma unroll
          for (int j = 0; j < 8; ++j) {
            float s = __fadd_rn(acc[i][j], bv[j]);
            if (s > tthr[r]) {           // strictly greater: earlier idx wins
              int p = TOPK - 1;
              while (p > 0 && tval[r][p-1] < s) {
                tval[r][p] = tval[r][p-1];
                tidx[r][p] = tidx[r][p-1];
                --p;
              }
              tval[r][p] = s;
              tidx[r][p] = n_base + tn * 8 + j;
              tthr[r] = tval[r][TOPK-1];
            }
          }
        }
      }
    }
  }

  __syncthreads();
  for (int r = tid; r < MBLK; r += NTH) {
    size_t off = ((size_t)split * M + m_base + r) * TOPK;
    #pragma unroll
    for (int j = 0; j < TOPK; ++j) { pval[off + j] = tval[r][j]; pidx[off + j] = tidx[r][j]; }
  }
}

// ---- stable nsplit-way merge + softmax (np order) + store ----------------
__global__ void er_merge(const float* __restrict__ pval, const int* __restrict__ pidx,
                         float* __restrict__ out, int M, int nsplit) {
  int m = blockIdx.x * blockDim.x + threadIdx.x;
  if (m >= M) return;
  int heads[4] = {0, 0, 0, 0};
  float v[TOPK]; int id[TOPK];
  for (int o = 0; o < TOPK; ++o) {
    float bvv = -FLT_MAX; int bi = 0x7fffffff; int bs = 0;
    for (int s = 0; s < nsplit; ++s) {
      if (heads[s] < TOPK) {
        size_t off = ((size_t)s * M + m) * TOPK + heads[s];
        float vv = pval[off]; int ii = pidx[off];
        if (vv > bvv || (vv == bvv && ii < bi)) { bvv = vv; bi = ii; bs = s; }
      }
    }
    v[o] = bvv; id[o] = bi; heads[bs]++;
  }
  float mx = v[0];
  float e[TOPK];
  #pragma unroll
  for (int j = 0; j < TOPK; ++j) e[j] = expf(__fadd_rn(v[j], -mx));
  float sum = __fadd_rn(
      __fadd_rn(__fadd_rn(e[0], e[1]), __fadd_rn(e[2], e[3])),
      __fadd_rn(__fadd_rn(e[4], e[5]), __fadd_rn(e[6], e[7])));
  const size_t SEC  = (size_t)M * TOPK;
  const size_t base = (size_t)m * TOPK;
  #pragma unroll
  for (int j = 0; j < TOPK; ++j) {
    out[base + j]         = bf16_rne_f32((float)id[j]);
    out[SEC + base + j]   = bf16_rne_f32(v[j]);
    out[2*SEC + base + j] = bf16_rne_f32(__fdiv_rn(e[j], sum));
  }
}

// ---------------- host ---------------------------------------------------
extern "C" void kernel_launch(void* const* d_in, const int* in_sizes, int n_in,
                              void* d_out, int out_size, void* d_ws, size_t ws_size,
                              hipStream_t stream) {
  const float* T   = (const float*)d_in[0];
  const float* S   = (const float*)d_in[1];
  const float* imp = (const float*)d_in[2];
  int M = in_sizes[0] / KDIM;   // 16384
  int N = in_sizes[1] / KDIM;   // 32768

  int nsplit = 4;               // 1024 blocks = 4/CU; degrade if ws is small
  while (nsplit > 1) {
    size_t need = (size_t)(M + N) * 4 + (size_t)nsplit * M * TOPK * 8;
    if (need <= ws_size) break;
    nsplit >>= 1;
  }

  float* nt   = (float*)d_ws;
  float* ns   = nt + M;
  float* pval = ns + N;
  int*   pidx = (int*)(pval + (size_t)nsplit * M * TOPK);
  float* out  = (float*)d_out;

  int mblocks = M / MBLK;       // 256
  er_norms<<<(4 * (M + N) + 255) / 256, 256, 0, stream>>>(T, S, nt, ns, M, N);
  er_cand<<<mblocks * nsplit, NTH, 0, stream>>>(T, S, imp, nt, ns,
                                                pval, pidx, M, N, nsplit, mblocks);
  er_merge<<<(M + 255) / 256, 256, 0, stream>>>(pval, pidx, out, M, nsplit);
}

// Round 15
// 8995.382 us; speedup vs baseline: 1.8035x; 1.8035x over previous
//
#include <hip/hip_runtime.h>
#include <hip/hip_bf16.h>
#include <float.h>

#define KDIM 512
#define MBLK 64
#define NBLK 256
#define KBLK 16
#define NTH  256
#define APAD 68     // 64+4
#define BROW 284    // 256 + 4*(256/32) spread slots; 284*4B = 16B-aligned rows
#define TOPK 8
// bank-spread column index: 16B gap every 32 floats; keeps any aligned
// 8-col group contiguous (b128 pair legal), staggers bank quads 8-way->4-way
#define BIDX(c) ((c) + (((c) >> 5) << 2))

// f32 whose high 16 bits are the RNE bf16 of v.
__device__ __forceinline__ float bf16_rne_f32(float v) {
  return __bfloat162float(__float2bfloat16(v));
}

// ---- row L2 norms in EXACT numpy pairwise order (unchanged, R13-proven) --
__global__ void er_norms(const float* __restrict__ T, const float* __restrict__ S,
                         float* __restrict__ nt, float* __restrict__ ns,
                         int M, int N) {
  int gid = blockIdx.x * blockDim.x + threadIdx.x;
  int row = gid >> 2;
  int b   = gid & 3;
  if (row >= M + N) return;
  const float* base = (row < M) ? (T + (size_t)row * KDIM)
                                : (S + (size_t)(row - M) * KDIM);
  const float4* p4 = (const float4*)(base + b * 128);
  float r[8];
  {
    float4 f0 = p4[0], f1 = p4[1];
    r[0] = __fmul_rn(f0.x, f0.x); r[1] = __fmul_rn(f0.y, f0.y);
    r[2] = __fmul_rn(f0.z, f0.z); r[3] = __fmul_rn(f0.w, f0.w);
    r[4] = __fmul_rn(f1.x, f1.x); r[5] = __fmul_rn(f1.y, f1.y);
    r[6] = __fmul_rn(f1.z, f1.z); r[7] = __fmul_rn(f1.w, f1.w);
  }
  #pragma unroll
  for (int i = 2; i < 32; i += 2) {
    float4 f0 = p4[i], f1 = p4[i + 1];
    r[0] = __fadd_rn(r[0], __fmul_rn(f0.x, f0.x));
    r[1] = __fadd_rn(r[1], __fmul_rn(f0.y, f0.y));
    r[2] = __fadd_rn(r[2], __fmul_rn(f0.z, f0.z));
    r[3] = __fadd_rn(r[3], __fmul_rn(f0.w, f0.w));
    r[4] = __fadd_rn(r[4], __fmul_rn(f1.x, f1.x));
    r[5] = __fadd_rn(r[5], __fmul_rn(f1.y, f1.y));
    r[6] = __fadd_rn(r[6], __fmul_rn(f1.z, f1.z));
    r[7] = __fadd_rn(r[7], __fmul_rn(f1.w, f1.w));
  }
  float B = __fadd_rn(__fadd_rn(__fadd_rn(r[0], r[1]), __fadd_rn(r[2], r[3])),
                      __fadd_rn(__fadd_rn(r[4], r[5]), __fadd_rn(r[6], r[7])));
  float t = __fadd_rn(B, __shfl_xor(B, 1, 64));
  float s = __fadd_rn(t, __shfl_xor(t, 2, 64));
  if (b == 0) {
    float nr = __fsqrt_rn(s);
    if (row < M) nt[row] = nr; else ns[row - M] = nr;
  }
}

// ---- candidate pass: normalized-f32 GEMM + per-split top-8 ---------------
// (NTH,2): VGPR cap 128 (hipcc rule: cap = 256/minwaves) -> no spill at ~100.
// KBLK=16 -> LDS 26.5KB -> 4 blocks/CU. Score arithmetic bit-identical R13.
__global__ __launch_bounds__(NTH, 2)
void er_cand(const float* __restrict__ A, const float* __restrict__ B,
             const float* __restrict__ imp,
             const float* __restrict__ nt, const float* __restrict__ ns,
             float* __restrict__ pval, int* __restrict__ pidx,
             int M, int N, int nsplit, int mblocks) {
  __shared__ float a_lds[KBLK][APAD];
  __shared__ float b_lds[KBLK][BROW];
  __shared__ float tval[MBLK][TOPK];
  __shared__ int   tidx[MBLK][TOPK];
  __shared__ float tthr[MBLK];

  const int tid    = threadIdx.x;
  const int mb     = blockIdx.x % mblocks;
  const int split  = blockIdx.x / mblocks;
  const int m_base = mb * MBLK;
  const int n_cols = N / nsplit;
  const int n_start = split * n_cols;
  const int ntiles  = n_cols / NBLK;
  const int tm = tid >> 5;        // rows tm*8..tm*8+7 (wave-exclusive)
  const int tn = tid & 31;        // cols tn*8..tn*8+7
  const int lane = tid & 63;

  if (tid < MBLK) {
    tthr[tid] = -FLT_MAX;
    #pragma unroll
    for (int j = 0; j < TOPK; ++j) { tval[tid][j] = -FLT_MAX; tidx[tid][j] = 0; }
  }
  __syncthreads();

  // staging coords: A 64x16 (1 float4/thr), B 256x16 (4 float4/thr)
  const int sarow = tid >> 2, saks = tid & 3;
  const int bread_off = BIDX(tn * 8);   // contiguous 8-col group, spread layout

  #pragma unroll 1
  for (int t = 0; t < ntiles; ++t) {
    const int n_base = n_start + t * NBLK;
    float acc[8][8];
    #pragma unroll
    for (int i = 0; i < 8; ++i)
      #pragma unroll
      for (int j = 0; j < 8; ++j) acc[i][j] = 0.f;

    float4 ar, br[4];
    ar = *(const float4*)&A[(size_t)(m_base + sarow) * KDIM + saks * 4];
    #pragma unroll
    for (int ii = 0; ii < 4; ++ii) {
      int u = tid + NTH * ii, row = u >> 2, ks = u & 3;
      br[ii] = *(const float4*)&B[(size_t)(n_base + row) * KDIM + ks * 4];
    }

    #pragma unroll 1
    for (int kc = 0; kc < KDIM / KBLK; ++kc) {
      __syncthreads();
      {   // stage A normalized (bit-same divides as R13)
        float dn = fmaxf(nt[m_base + sarow], 1e-12f);
        a_lds[saks*4+0][sarow] = __fdiv_rn(ar.x, dn);
        a_lds[saks*4+1][sarow] = __fdiv_rn(ar.y, dn);
        a_lds[saks*4+2][sarow] = __fdiv_rn(ar.z, dn);
        a_lds[saks*4+3][sarow] = __fdiv_rn(ar.w, dn);
      }
      #pragma unroll
      for (int ii = 0; ii < 4; ++ii) {
        int u = tid + NTH * ii, row = u >> 2, ks = u & 3;
        float dn = fmaxf(ns[n_base + row], 1e-12f);
        int c = BIDX(row);
        b_lds[ks*4+0][c] = __fdiv_rn(br[ii].x, dn);
        b_lds[ks*4+1][c] = __fdiv_rn(br[ii].y, dn);
        b_lds[ks*4+2][c] = __fdiv_rn(br[ii].z, dn);
        b_lds[ks*4+3][c] = __fdiv_rn(br[ii].w, dn);
      }
      __syncthreads();
      if (kc + 1 < KDIM / KBLK) {
        int kb = (kc + 1) * KBLK;
        ar = *(const float4*)&A[(size_t)(m_base + sarow) * KDIM + kb + saks * 4];
        #pragma unroll
        for (int ii = 0; ii < 4; ++ii) {
          int u = tid + NTH * ii, row = u >> 2, ks = u & 3;
          br[ii] = *(const float4*)&B[(size_t)(n_base + row) * KDIM + kb + ks * 4];
        }
      }
      // sequential-k FMA chain, k ascending — bit-identical to R13
      #pragma unroll 16
      for (int k = 0; k < KBLK; ++k) {
        const float4* ap = (const float4*)&a_lds[k][tm * 8];
        const float4* bp = (const float4*)&b_lds[k][bread_off];
        float4 a0 = ap[0], a1 = ap[1], b0 = bp[0], b1 = bp[1];
        float av[8] = {a0.x,a0.y,a0.z,a0.w,a1.x,a1.y,a1.z,a1.w};
        float bw[8] = {b0.x,b0.y,b0.z,b0.w,b1.x,b1.y,b1.z,b1.w};
        #pragma unroll
        for (int i = 0; i < 8; ++i)
          #pragma unroll
          for (int j = 0; j < 8; ++j)
            acc[i][j] = fmaf(av[i], bw[j], acc[i][j]);
      }
    }

    // epilogue: score = dot + bias (separate RNE add), running top-8
    float bv[8];
    #pragma unroll
    for (int j = 0; j < 8; ++j) bv[j] = __fmul_rn(0.1f, imp[n_base + tn * 8 + j]);

    int need = 0;
    #pragma unroll
    for (int i = 0; i < 8; ++i) {
      float thr = tthr[tm * 8 + i];
      #pragma unroll
      for (int j = 0; j < 8; ++j) {
        float s = __fadd_rn(acc[i][j], bv[j]);
        need |= (s > thr) ? 1 : 0;
      }
    }
    unsigned long long mask = __ballot(need);
    while (mask) {                       // ascending lane == ascending n
      int cur = __ffsll(mask) - 1;
      mask &= mask - 1;
      if (lane == cur) {
        #pragma unroll
        for (int i = 0; i < 8; ++i) {
          int r = tm * 8 + i;
          #pragma unroll
          for (int j = 0; j < 8; ++j) {
            float s = __fadd_rn(acc[i][j], bv[j]);
            if (s > tthr[r]) {           // strictly greater: earlier idx wins
              int p = TOPK - 1;
              while (p > 0 && tval[r][p-1] < s) {
                tval[r][p] = tval[r][p-1];
                tidx[r][p] = tidx[r][p-1];
                --p;
              }
              tval[r][p] = s;
              tidx[r][p] = n_base + tn * 8 + j;
              tthr[r] = tval[r][TOPK-1];
            }
          }
        }
      }
    }
  }

  __syncthreads();
  for (int r = tid; r < MBLK; r += NTH) {
    size_t off = ((size_t)split * M + m_base + r) * TOPK;
    #pragma unroll
    for (int j = 0; j < TOPK; ++j) { pval[off + j] = tval[r][j]; pidx[off + j] = tidx[r][j]; }
  }
}

// ---- stable nsplit-way merge + softmax (np order) + store (R14-proven) ---
__global__ void er_merge(const float* __restrict__ pval, const int* __restrict__ pidx,
                         float* __restrict__ out, int M, int nsplit) {
  int m = blockIdx.x * blockDim.x + threadIdx.x;
  if (m >= M) return;
  int heads[4] = {0, 0, 0, 0};
  float v[TOPK]; int id[TOPK];
  for (int o = 0; o < TOPK; ++o) {
    float bvv = -FLT_MAX; int bi = 0x7fffffff; int bs = 0;
    for (int s = 0; s < nsplit; ++s) {
      if (heads[s] < TOPK) {
        size_t off = ((size_t)s * M + m) * TOPK + heads[s];
        float vv = pval[off]; int ii = pidx[off];
        if (vv > bvv || (vv == bvv && ii < bi)) { bvv = vv; bi = ii; bs = s; }
      }
    }
    v[o] = bvv; id[o] = bi; heads[bs]++;
  }
  float mx = v[0];
  float e[TOPK];
  #pragma unroll
  for (int j = 0; j < TOPK; ++j) e[j] = expf(__fadd_rn(v[j], -mx));
  float sum = __fadd_rn(
      __fadd_rn(__fadd_rn(e[0], e[1]), __fadd_rn(e[2], e[3])),
      __fadd_rn(__fadd_rn(e[4], e[5]), __fadd_rn(e[6], e[7])));
  const size_t SEC  = (size_t)M * TOPK;
  const size_t base = (size_t)m * TOPK;
  #pragma unroll
  for (int j = 0; j < TOPK; ++j) {
    out[base + j]         = bf16_rne_f32((float)id[j]);
    out[SEC + base + j]   = bf16_rne_f32(v[j]);
    out[2*SEC + base + j] = bf16_rne_f32(__fdiv_rn(e[j], sum));
  }
}

// ---------------- host ---------------------------------------------------
extern "C" void kernel_launch(void* const* d_in, const int* in_sizes, int n_in,
                              void* d_out, int out_size, void* d_ws, size_t ws_size,
                              hipStream_t stream) {
  const float* T   = (const float*)d_in[0];
  const float* S   = (const float*)d_in[1];
  const float* imp = (const float*)d_in[2];
  int M = in_sizes[0] / KDIM;   // 16384
  int N = in_sizes[1] / KDIM;   // 32768

  int nsplit = 4;               // grid 1024 = exactly 4 blocks/CU (R14: ws fits)
  while (nsplit > 1) {
    size_t need = (size_t)(M + N) * 4 + (size_t)nsplit * M * TOPK * 8;
    if (need <= ws_size) break;
    nsplit >>= 1;
  }

  float* nt   = (float*)d_ws;
  float* ns   = nt + M;
  float* pval = ns + N;
  int*   pidx = (int*)(pval + (size_t)nsplit * M * TOPK);
  float* out  = (float*)d_out;

  int mblocks = M / MBLK;       // 256
  er_norms<<<(4 * (M + N) + 255) / 256, 256, 0, stream>>>(T, S, nt, ns, M, N);
  er_cand<<<mblocks * nsplit, NTH, 0, stream>>>(T, S, imp, nt, ns,
                                                pval, pidx, M, N, nsplit, mblocks);
  er_merge<<<(M + 255) / 256, 256, 0, stream>>>(pval, pidx, out, M, nsplit);
}